// Round 8
// baseline (2564.073 us; speedup 1.0000x reference)
//
#include <hip/hip_runtime.h>
#include <hip/hip_fp16.h>
#include <math.h>

// Problem constants
#define NB 64
#define NS 128
#define ND 128
#define NV 512
#define NC 256
#define NN 256
#define NM 64
#define NG 1024
#define KIH 192
#define K2  448      // unified GEMV depth: [emb(128) | rv(64) | h(256)]
#define KZ  320
#define HST 208
#define MPAD 65
#define KPW 56       // k-slice per wave, mono (8 waves * 56 = 448)
#define KPW4 28      // k-slice per wave, main4 (16 waves * 28 = 448)
#define G_PER_R 28672 // 448*64 uint2 per quarter

// ws layout: fp16 weights packed as uint2 (4 halves each), then fp32 biases, then hrv
#define U2_GEND 114688      // gate weights: [4 quarters][448 k][64 ch] uint2
#define U2_OUT  128000      // head weights: [256 k][52 cq] -> 13312 uint2
#define U2_END  168960      // out weights:  [320 k][128 cq] -> 40960 uint2
#define F_BSUM 337920       // 1024 floats (= U2_END*2)
#define F_HB   338944       // 208 floats (pad to 256)
#define F_HRV  339200       // 8192*320 floats
#define WS_SPLIT_BYTES 11842560u
#define PREP_ZERO 384       // stp(256) + presence(64) + confirm(64)
#define PREP_ITEMS (U2_END + NG + HST + PREP_ZERO)

// exchange region: tail of out buffer (out = 64*128*512 floats = 16.7MB; in split
// mode the tail is scratch until ntm_logits overwrites ALL of out at the end)
#define OUT_FLOATS (NB * NS * NV)
#define XCHG_FLOATS 33280   // xh 2*64*256 + stp 256 + pres 64 + conf 64 + pad

// LDS layout (floats)
#define L_MEM 0              // 256*65
#define L_H   16640          // 256
#define L_C   16896          // 256
#define L_RW  17152          // 256
#define L_W   17408          // 256
#define L_RV  17664          // 64
#define L_CI  17728          // 448
#define L_HD  18176          // 208 (198 = |key|)
#define L_SIM 18384          // 256
#define L_TOK 18640          // 128 (ints)
#define L_PART 18768         // 4096 (16B aligned: 18768*4 % 16 == 0)
#define L_BS  22864          // 1024 (bias sums, LDS-cached)
#define L_HB2 23888          // 208  (head biases, LDS-cached)
#define SMEM_FLOATS 24096
#define SMEM_BYTES (SMEM_FLOATS * 4)   // 96384 B -> 1 block/CU (2x exceeds 160KB)

__device__ __forceinline__ float sigf(float x) { return 1.0f / (1.0f + __expf(-x)); }
__device__ __forceinline__ float splus(float x) { return (x > 20.f) ? x : log1pf(__expf(x)); }
__device__ __forceinline__ float tanhf_fast(float x) {
  if (fabsf(x) > 15.f) return copysignf(1.f, x);
  float e = __expf(2.f * x);
  return (e - 1.f) / (e + 1.f);
}

__device__ __forceinline__ float hlo(unsigned u) {
  unsigned short s = (unsigned short)(u & 0xffffu);
  _Float16 h;
  __builtin_memcpy(&h, &s, 2);
  return (float)h;
}
__device__ __forceinline__ float hhi(unsigned u) {
  unsigned short s = (unsigned short)(u >> 16);
  _Float16 h;
  __builtin_memcpy(&h, &s, 2);
  return (float)h;
}
__device__ __forceinline__ unsigned short f2h(float f) {  // RNE
  _Float16 h = (_Float16)f;
  unsigned short s;
  __builtin_memcpy(&s, &h, 2);
  return s;
}

#define FMA4(G, A) \
  acc.x = fmaf(hlo((G).x), (A), acc.x); acc.y = fmaf(hhi((G).x), (A), acc.y); \
  acc.z = fmaf(hlo((G).y), (A), acc.z); acc.w = fmaf(hhi((G).y), (A), acc.w);

__device__ float head_w(int c, int k, const float* kW, const float* eW, const float* aW,
                        const float* sW, const float* bW, const float* gW, const float* gaW) {
  if (c < 64)  return kW[c * NC + k];
  if (c < 128) return eW[(c - 64) * NC + k];
  if (c < 192) return aW[(c - 128) * NC + k];
  if (c < 195) return sW[(c - 192) * NC + k];
  if (c == 195) return bW[k];
  if (c == 196) return gW[k];
  if (c == 197) return gaW[k];
  return 0.0f;
}

// ---------------- Preprocess: repack weights (channel-quad gate layout) ----------------
__global__ void ntm_prep(const float* __restrict__ W_ih, const float* __restrict__ W_hh,
                         const float* __restrict__ b_ih, const float* __restrict__ b_hh,
                         const float* __restrict__ key_W, const float* __restrict__ key_b,
                         const float* __restrict__ beta_W, const float* __restrict__ beta_b,
                         const float* __restrict__ gate_W, const float* __restrict__ gate_b,
                         const float* __restrict__ shift_W, const float* __restrict__ shift_b,
                         const float* __restrict__ gamma_W, const float* __restrict__ gamma_b,
                         const float* __restrict__ erase_W, const float* __restrict__ erase_b,
                         const float* __restrict__ add_W, const float* __restrict__ add_b,
                         const float* __restrict__ out_W, float* __restrict__ ws,
                         unsigned* __restrict__ zaux)
{
  uint2* w4 = (uint2*)ws;
  for (int idx = blockIdx.x * blockDim.x + threadIdx.x; idx < PREP_ITEMS;
       idx += gridDim.x * blockDim.x) {
    if (idx < U2_GEND) {
      int r = idx / G_PER_R;
      int i = idx - r * G_PER_R;
      int k = i >> 6, cp = i & 63;
      int c = (r << 6) | cp;
      float v[4];
      #pragma unroll
      for (int j = 0; j < 4; ++j) {
        int row = j * NC + c;
        v[j] = (k < KIH) ? W_ih[row * KIH + k] : W_hh[row * NC + (k - KIH)];
      }
      uint2 p;
      p.x = (unsigned)f2h(v[0]) | ((unsigned)f2h(v[1]) << 16);
      p.y = (unsigned)f2h(v[2]) | ((unsigned)f2h(v[3]) << 16);
      w4[idx] = p;
    } else if (idx < U2_OUT) {
      int i = idx - U2_GEND, k = i / 52, cq = i % 52;
      float v[4];
      #pragma unroll
      for (int j = 0; j < 4; ++j)
        v[j] = head_w(cq * 4 + j, k, key_W, erase_W, add_W, shift_W, beta_W, gate_W, gamma_W);
      uint2 p;
      p.x = (unsigned)f2h(v[0]) | ((unsigned)f2h(v[1]) << 16);
      p.y = (unsigned)f2h(v[2]) | ((unsigned)f2h(v[3]) << 16);
      w4[idx] = p;
    } else if (idx < U2_END) {
      int i = idx - U2_OUT, k = i >> 7, og = i & 127;
      float v[4];
      #pragma unroll
      for (int j = 0; j < 4; ++j) v[j] = out_W[(og * 4 + j) * KZ + k];
      uint2 p;
      p.x = (unsigned)f2h(v[0]) | ((unsigned)f2h(v[1]) << 16);
      p.y = (unsigned)f2h(v[2]) | ((unsigned)f2h(v[3]) << 16);
      w4[idx] = p;
    } else if (idx < U2_END + NG) {
      int o = idx - U2_END;
      ws[F_BSUM + o] = b_ih[o] + b_hh[o];
    } else if (idx < U2_END + NG + HST) {
      int c = idx - U2_END - NG;
      float v;
      if (c < 64)       v = key_b[c];
      else if (c < 128) v = erase_b[c - 64];
      else if (c < 192) v = add_b[c - 128];
      else if (c < 195) v = shift_b[c - 192];
      else if (c == 195) v = beta_b[0];
      else if (c == 196) v = gate_b[0];
      else               v = gamma_b[0];
      ws[F_HB + c] = v;
    } else {
      zaux[idx - (U2_END + NG + HST)] = 0u;
    }
  }
}

// ---------------- Split main: 4 blocks per batch, L2-streamed quarter weights ----------------
// 7 barriers/step (was 9): head GEMV reduced in-wave; acts & cosine fused (cosine
// uses RAW key, normalization folded into addressing as beta/|key| — algebraically
// identical incl. eps clamps); rv-partials + memory update merged into one s_mem
// pass, rv combine deferred into next step's ci fill (s_part read-only there).
__global__ void __launch_bounds__(1024)
ntm_main4(const int* __restrict__ x, const float* __restrict__ emb,
          const float* __restrict__ mem_init,
          const float* __restrict__ ws, unsigned* __restrict__ xaux)
{
  const int bid = blockIdx.x;
  const int b = bid & 63;
  const int r = bid >> 6;          // channel quarter
  const int tid = threadIdx.x;
  const int w = tid >> 6, lane = tid & 63;
  unsigned* xh   = xaux;           // [2][NB][NC]
  unsigned* stp  = xaux + 32768;   // per-sibling step tags [NB][4]
  unsigned* pres = xaux + 33024;   // presence bitmask [NB]
  unsigned* conf = xaux + 33088;   // confirm bitmask [NB]
  const uint2* G4   = (const uint2*)ws;
  const uint2* HWT4 = G4 + U2_GEND;
  const float* bsum = ws + F_BSUM;
  const float* hb   = ws + F_HB;
  float* hrv = (float*)(ws + F_HRV);

  __shared__ float sm[SMEM_FLOATS];
  float* s_mem = sm + L_MEM;
  float* s_h   = sm + L_H;
  float* s_c   = sm + L_C;
  float* s_rw  = sm + L_RW;
  float* s_w   = sm + L_W;
  float* s_ci  = sm + L_CI;
  float* s_hd  = sm + L_HD;
  float* s_sim = sm + L_SIM;
  int*   s_tok = (int*)(sm + L_TOK);
  float* s_part = sm + L_PART;
  float4* s_part4 = (float4*)s_part;
  float* s_bs  = sm + L_BS;
  float* s_hb  = sm + L_HB2;

  for (int i = tid; i < NN * NM; i += 1024) {
    int n = i >> 6, m = i & 63;
    s_mem[n * MPAD + m] = mem_init[(size_t)b * (NN * NM) + i];
  }
  if (tid < NS) s_tok[tid] = x[b * NS + tid];
  if (tid < NC) { s_h[tid] = 0.f; s_c[tid] = 0.f; }
  if (tid < NN) s_rw[tid] = 0.f;
  s_part[tid] = 0.f;                 // rv partials = 0 at t=0
  if (tid < NG) s_bs[tid] = bsum[tid];
  if (tid < HST) s_hb[tid] = hb[tid];
  __syncthreads();

  // ---- co-residency handshake (bounded; cannot deadlock) ----
  if (tid == 0) {
    __hip_atomic_fetch_or(pres + b, 1u << r, __ATOMIC_RELEASE, __HIP_MEMORY_SCOPE_AGENT);
    int ok = 0;
    for (int i = 0; i < 40000; ++i) {
      if (__hip_atomic_load(pres + b, __ATOMIC_ACQUIRE, __HIP_MEMORY_SCOPE_AGENT) == 15u) {
        ok = 1; break;
      }
      __builtin_amdgcn_s_sleep(2);
    }
    int ok2 = 0;
    if (ok) {
      __hip_atomic_fetch_or(conf + b, 1u << r, __ATOMIC_RELEASE, __HIP_MEMORY_SCOPE_AGENT);
      for (int i = 0; i < 80000; ++i) {
        if (__hip_atomic_load(conf + b, __ATOMIC_ACQUIRE, __HIP_MEMORY_SCOPE_AGENT) == 15u) {
          ok2 = 1; break;
        }
        __builtin_amdgcn_s_sleep(2);
      }
    }
    ((int*)sm)[L_SIM] = ok2;
  }
  __syncthreads();
  const bool coop = (((int*)sm)[L_SIM] != 0);
  __syncthreads();
  if (!coop && r != 0) return;   // fallback: only r==0 continues, self-contained

  const int rq_lo = coop ? r : 0;      // quarters this block computes
  const int rq_hi = coop ? r + 1 : 4;

  for (int t = 0; t < NS; ++t) {
    // ---- P-A: ci = [emb, rv(sum of partials), h_prev]; hrv store for t-1 ----
    if (tid < K2) {
      int tok = s_tok[t];
      float v;
      if (tid < ND) v = emb[tok * ND + tid];
      else if (tid < KIH) {
        int m = tid - ND;
        float a = 0.f;
        #pragma unroll
        for (int q = 0; q < 16; ++q) a += s_part[q * 64 + m];
        v = a;
      } else v = s_h[tid - KIH];
      s_ci[tid] = v;
    }
    if (t > 0) {
      if (coop) {
        if (tid >= 448 && tid < 528) {    // 80 floats per sibling (waves 7)
          int i = tid - 448;
          float* dst = hrv + (size_t)(b * NS + (t - 1)) * KZ;
          if (i < 64) dst[r * 64 + i] = s_h[r * 64 + i];
          else {
            int m = r * 16 + (i - 64);
            float a = 0.f;
            #pragma unroll
            for (int q = 0; q < 16; ++q) a += s_part[q * 64 + m];
            dst[256 + m] = a;
          }
        }
      } else if (tid >= 448 && tid < 768) {
        int i = tid - 448;
        float v;
        if (i < NC) v = s_h[i];
        else {
          int m = i - NC;
          float a = 0.f;
          #pragma unroll
          for (int q = 0; q < 16; ++q) a += s_part[q * 64 + m];
          v = a;
        }
        hrv[(size_t)(b * NS + (t - 1)) * KZ + i] = v;
      }
    }
    __syncthreads();  // S1

    // ---- P2/P3: gate GEMV (L2-streamed) + LSTM cell, per owned quarter ----
    for (int rr = rq_lo; rr < rq_hi; ++rr) {
      {
        float4 acc = {0.f, 0.f, 0.f, 0.f};
        const uint2* gp = G4 + rr * G_PER_R + (w * KPW4) * 64 + lane;
        const float* cip = s_ci + w * KPW4;
        #pragma unroll
        for (int kk = 0; kk < KPW4; kk += 4) {
          uint2 g0 = gp[(kk + 0) * 64];
          uint2 g1 = gp[(kk + 1) * 64];
          uint2 g2 = gp[(kk + 2) * 64];
          uint2 g3 = gp[(kk + 3) * 64];
          float4 a4 = *(const float4*)(cip + kk);
          FMA4(g0, a4.x);
          FMA4(g1, a4.y);
          FMA4(g2, a4.z);
          FMA4(g3, a4.w);
        }
        s_part4[w * 64 + lane] = acc;
      }
      __syncthreads();  // S2
      if (tid < 64) {
        int c = (rr << 6) | tid;
        float gi = s_bs[c], gf = s_bs[NC + c], gg = s_bs[2 * NC + c], go = s_bs[3 * NC + c];
        #pragma unroll
        for (int q = 0; q < 16; ++q) {
          float4 p = s_part4[q * 64 + tid];
          gi += p.x; gf += p.y; gg += p.z; go += p.w;
        }
        if (coop) {
          float cn = sigf(gf) * s_c[tid] + sigf(gi) * tanhf_fast(gg);
          s_c[tid] = cn;
          float hn = sigf(go) * tanhf_fast(cn);
          s_h[c] = hn;   // own chunk: straight to LDS
          __hip_atomic_store(xh + (t & 1) * (NB * NC) + b * NC + c, __float_as_uint(hn),
                             __ATOMIC_RELAXED, __HIP_MEMORY_SCOPE_AGENT);
        } else {
          float cn = sigf(gf) * s_c[c] + sigf(gi) * tanhf_fast(gg);
          s_c[c] = cn;
          s_h[c] = sigf(go) * tanhf_fast(cn);
        }
      }
      if (!coop) __syncthreads();
    }

    if (coop) {
      // ---- exchange: release tag, relaxed per-sibling polls, relaxed gather ----
      if (tid == 0) {
        __hip_atomic_store(stp + b * 4 + r, (unsigned)(t + 1),
                           __ATOMIC_RELEASE, __HIP_MEMORY_SCOPE_AGENT);
      } else if (w >= 1 && w <= 3) {
        int sib = (r + w) & 3;
        const unsigned tgt = (unsigned)(t + 1);
        while (__hip_atomic_load(stp + b * 4 + sib, __ATOMIC_RELAXED,
                                 __HIP_MEMORY_SCOPE_AGENT) < tgt) {}
        unsigned hv = __hip_atomic_load(xh + (t & 1) * (NB * NC) + b * NC + (sib << 6) + lane,
                                        __ATOMIC_RELAXED, __HIP_MEMORY_SCOPE_AGENT);
        s_h[(sib << 6) + lane] = __uint_as_float(hv);
      }
      __syncthreads();  // S3
    }

    // ---- P4: head GEMV in-wave (4 waves x 13 cq, k split 4x64, shfl reduce) ----
    if (tid < 256) {
      int kq = lane >> 4, c16 = lane & 15;
      int cq = w * 13 + ((c16 < 13) ? c16 : 12);   // clamp keeps loads in-bounds
      float4 acc = {0.f, 0.f, 0.f, 0.f};
      const uint2* ph = HWT4 + (kq * 64) * 52 + cq;
      const float* hp = s_h + kq * 64;
      #pragma unroll 8
      for (int i = 0; i < 64; ++i) {
        uint2 wv = ph[i * 52];
        float a = hp[i];
        FMA4(wv, a);
      }
      acc.x += __shfl_xor(acc.x, 16); acc.y += __shfl_xor(acc.y, 16);
      acc.z += __shfl_xor(acc.z, 16); acc.w += __shfl_xor(acc.w, 16);
      acc.x += __shfl_xor(acc.x, 32); acc.y += __shfl_xor(acc.y, 32);
      acc.z += __shfl_xor(acc.z, 32); acc.w += __shfl_xor(acc.w, 32);
      if (kq == 0 && c16 < 13) {
        float4 bb = *(const float4*)(s_hb + cq * 4);
        acc.x += bb.x; acc.y += bb.y; acc.z += bb.z; acc.w += bb.w;
        *(float4*)(s_hd + cq * 4) = acc;   // RAW head outputs
      }
    }
    __syncthreads();  // S4

    // ---- P5||P6: activations (threads 0-255) in parallel with cosine dots
    //      on RAW key (threads 256-767); key stays raw in s_hd[0..64) ----
    if (tid < 256) {
      float val = (tid < HST) ? s_hd[tid] : 0.f;
      int wv = tid >> 6;
      if (wv == 0) {            // |key| only (normalization folded into P7)
        float ss = val * val;
        for (int off = 32; off; off >>= 1) ss += __shfl_xor(ss, off);
        if (lane == 0) s_hd[198] = fmaxf(sqrtf(ss), 1e-12f);
      } else if (wv == 1) {     // erase: sigmoid
        s_hd[tid] = sigf(val);
      } else if (wv == 2) {     // add: tanh
        s_hd[tid] = tanhf_fast(val);
      } else {                  // wave 3: shift softmax + scalars
        int l = tid & 63;
        float a0 = __shfl(val, 0), a1 = __shfl(val, 1), a2 = __shfl(val, 2);
        float mx = fmaxf(a0, fmaxf(a1, a2));
        float e0 = __expf(a0 - mx), e1 = __expf(a1 - mx), e2 = __expf(a2 - mx);
        float ss = e0 + e1 + e2;
        float rr = 0.f;
        if (l == 0) rr = e0 / ss;
        else if (l == 1) rr = e1 / ss;
        else if (l == 2) rr = e2 / ss;
        else if (l == 3) rr = splus(val);          // beta  (col 195)
        else if (l == 4) rr = sigf(val);           // gate  (col 196)
        else if (l == 5) rr = 1.0f + splus(val);   // gamma (col 197)
        if (l < 6) s_hd[192 + l] = rr;             // NOTE: 198 holds |key|
      }
    } else if (tid < 768) {
      int idx = tid - 256, n = idx >> 1, half = idx & 1;
      const float* mrow = s_mem + n * MPAD + half * 32;
      const float* kp = s_hd + half * 32;          // RAW key
      float dot = 0.f, sq = 0.f;
      #pragma unroll
      for (int i = 0; i < 32; ++i) {
        float mv = mrow[i];
        dot = fmaf(mv, kp[i], dot);
        sq  = fmaf(mv, mv, sq);
      }
      dot += __shfl_xor(dot, 1);
      sq  += __shfl_xor(sq, 1);
      if (half == 0) s_sim[n] = dot / fmaxf(sqrtf(sq), 1e-12f);  // /|mem| only
    }
    __syncthreads();  // S5

    // ---- P7: addressing chain in one wave (4 slots/lane) ----
    if (tid < 64) {
      int l = tid;
      float keyn = s_hd[198];
      float bk = s_hd[195] / keyn;     // beta / |key|  (completes cosine sim)
      float gate = s_hd[196], gamma = s_hd[197];
      float sh0 = s_hd[192], sh1 = s_hd[193], sh2 = s_hd[194];
      float v0 = bk * s_sim[l], v1 = bk * s_sim[64 + l];
      float v2 = bk * s_sim[128 + l], v3 = bk * s_sim[192 + l];
      float mx = fmaxf(fmaxf(v0, v1), fmaxf(v2, v3));
      for (int off = 32; off; off >>= 1) mx = fmaxf(mx, __shfl_xor(mx, off));
      float e0 = __expf(v0 - mx), e1 = __expf(v1 - mx);
      float e2 = __expf(v2 - mx), e3 = __expf(v3 - mx);
      float s = e0 + e1 + e2 + e3;
      for (int off = 32; off; off >>= 1) s += __shfl_xor(s, off);
      float inv = 1.0f / s, omg = 1.0f - gate;
      float wg[4];
      wg[0] = gate * e0 * inv + omg * s_rw[l];
      wg[1] = gate * e1 * inv + omg * s_rw[64 + l];
      wg[2] = gate * e2 * inv + omg * s_rw[128 + l];
      wg[3] = gate * e3 * inv + omg * s_rw[192 + l];
      float p[4]; float ps = 0.f;
      #pragma unroll
      for (int j = 0; j < 4; ++j) {
        float cu = (l == 0) ? wg[(j + 1) & 3] : wg[j];
        float up = __shfl(cu, (l + 1) & 63);
        float cd = (l == 63) ? wg[(j + 3) & 3] : wg[j];
        float dn = __shfl(cd, (l + 63) & 63);
        float wn = fmaf(sh0, up, fmaf(sh1, wg[j], sh2 * dn));
        p[j] = exp2f(gamma * __log2f(wn));   // w^gamma, w>=0
        ps += p[j];
      }
      for (int off = 32; off; off >>= 1) ps += __shfl_xor(ps, off);
      float invp = 1.0f / ps;
      #pragma unroll
      for (int j = 0; j < 4; ++j) {
        float wv = p[j] * invp;
        s_w[l + 64 * j] = wv;
        s_rw[l + 64 * j] = wv;
      }
    }
    __syncthreads();  // S6

    // ---- P8: rv partials + memory update in ONE s_mem pass ----
    {
      int m = tid & 63, q = tid >> 6;
      float er = s_hd[64 + m], ad = s_hd[128 + m];
      float acc = 0.f;
      int n0 = q * 16;
      #pragma unroll
      for (int i = 0; i < 16; ++i) {
        int n = n0 + i;
        float wv = s_w[n];
        float v = s_mem[n * MPAD + m];
        acc = fmaf(wv, v, acc);
        s_mem[n * MPAD + m] = v * (1.f - wv * er) + wv * ad;
      }
      s_part[q * 64 + m] = acc;   // combined into ci / hrv next step
    }
    __syncthreads();  // S7
  }

  // final hrv store (rv summed from partials of t = NS-1)
  if (coop) {
    if (tid >= 448 && tid < 528) {
      int i = tid - 448;
      float* dst = hrv + (size_t)(b * NS + NS - 1) * KZ;
      if (i < 64) dst[r * 64 + i] = s_h[r * 64 + i];
      else {
        int m = r * 16 + (i - 64);
        float a = 0.f;
        #pragma unroll
        for (int q = 0; q < 16; ++q) a += s_part[q * 64 + m];
        dst[256 + m] = a;
      }
    }
  } else if (tid >= 448 && tid < 768) {
    int i = tid - 448;
    float v;
    if (i < NC) v = s_h[i];
    else {
      int m = i - NC;
      float a = 0.f;
      #pragma unroll
      for (int q = 0; q < 16; ++q) a += s_part[q * 64 + m];
      v = a;
    }
    hrv[(size_t)(b * NS + NS - 1) * KZ + i] = v;
  }
}

// ---------------- Mono fallback (small ws): one block per batch, streamed weights ----------------
__launch_bounds__(512, 1)
__global__ void ntm_mono(const int* __restrict__ x, const float* __restrict__ emb,
                         const float* __restrict__ out_b, const float* __restrict__ mem_init,
                         const float* __restrict__ ws, float* __restrict__ out)
{
  const int b = blockIdx.x;
  const int tid = threadIdx.x;
  const int w = tid >> 6, lane = tid & 63;
  const uint2* G4   = (const uint2*)ws;
  const uint2* HWT4 = G4 + U2_GEND;
  const uint2* OUT4 = G4 + U2_OUT;
  const float* bsum = ws + F_BSUM;
  const float* hb   = ws + F_HB;

  extern __shared__ float sm[];
  float* s_mem = sm + L_MEM;
  float* s_h   = sm + L_H;
  float* s_c   = sm + L_C;
  float* s_rw  = sm + L_RW;
  float* s_w   = sm + L_W;
  float* s_rv  = sm + L_RV;
  float* s_ci  = sm + L_CI;
  float* s_hd  = sm + L_HD;
  float* s_sim = sm + L_SIM;
  int*   s_tok = (int*)(sm + L_TOK);
  float* s_part = sm + L_PART;
  float4* s_part4 = (float4*)s_part;

  for (int i = tid; i < NN * NM; i += 512) {
    int n = i >> 6, m = i & 63;
    s_mem[n * MPAD + m] = mem_init[(size_t)b * (NN * NM) + i];
  }
  if (tid < NS) s_tok[tid] = x[b * NS + tid];
  if (tid < NC) { s_h[tid] = 0.f; s_c[tid] = 0.f; }
  if (tid < NN) s_rw[tid] = 0.f;
  if (tid < NM) s_rv[tid] = 0.f;
  __syncthreads();

  for (int t = 0; t < NS; ++t) {
    if (tid < K2) {
      int tok = s_tok[t];
      s_ci[tid] = (tid < ND) ? emb[tok * ND + tid]
                : (tid < KIH) ? s_rv[tid - ND] : s_h[tid - KIH];
    }
    __syncthreads();

    for (int rr = 0; rr < 4; ++rr) {
      {
        float4 acc = {0.f, 0.f, 0.f, 0.f};
        const uint2* gp = G4 + rr * G_PER_R + (w * KPW) * 64 + lane;
        const float* cip = s_ci + w * KPW;
        #pragma unroll 8
        for (int kk = 0; kk < KPW; ++kk) {
          uint2 g = gp[kk * 64];
          float a = cip[kk];
          FMA4(g, a);
        }
        s_part4[w * 64 + lane] = acc;
      }
      __syncthreads();
      if (tid < 64) {
        int c = (rr << 6) | tid;
        float gi = bsum[c], gf = bsum[NC + c], gg = bsum[2 * NC + c], go = bsum[3 * NC + c];
        #pragma unroll
        for (int q = 0; q < 8; ++q) {
          float4 p = s_part4[q * 64 + tid];
          gi += p.x; gf += p.y; gg += p.z; go += p.w;
        }
        float cn = sigf(gf) * s_c[c] + sigf(gi) * tanhf_fast(gg);
        s_c[c] = cn;
        s_h[c] = sigf(go) * tanhf_fast(cn);
      }
      __syncthreads();
    }

    if (tid < 416) {
      int cq = tid % 52, q = tid / 52;
      float4 acc = {0.f, 0.f, 0.f, 0.f};
      const uint2* ph = HWT4 + (q * 32) * 52 + cq;
      const float* hp = s_h + q * 32;
      #pragma unroll 8
      for (int kk = 0; kk < 32; ++kk) {
        uint2 wv = ph[kk * 52];
        float a = hp[kk];
        FMA4(wv, a);
      }
      s_part4[q * 52 + cq] = acc;
    }
    __syncthreads();

    if (tid < 256) {
      float val = 0.f;
      if (tid < HST) {
        val = hb[tid];
        #pragma unroll
        for (int q = 0; q < 8; ++q) val += s_part[q * HST + tid];
      }
      int wv = tid >> 6;
      if (wv == 0) {
        float ss = val * val;
        for (int off = 32; off; off >>= 1) ss += __shfl_xor(ss, off);
        s_hd[tid] = val / fmaxf(sqrtf(ss), 1e-12f);
      } else if (wv == 1) {
        s_hd[tid] = sigf(val);
      } else if (wv == 2) {
        s_hd[tid] = tanhf_fast(val);
      } else {
        int l = tid & 63;
        float a0 = __shfl(val, 0), a1 = __shfl(val, 1), a2 = __shfl(val, 2);
        float mx = fmaxf(a0, fmaxf(a1, a2));
        float e0 = __expf(a0 - mx), e1 = __expf(a1 - mx), e2 = __expf(a2 - mx);
        float ss = e0 + e1 + e2;
        float rr = 0.f;
        if (l == 0) rr = e0 / ss;
        else if (l == 1) rr = e1 / ss;
        else if (l == 2) rr = e2 / ss;
        else if (l == 3) rr = splus(val);
        else if (l == 4) rr = sigf(val);
        else if (l == 5) rr = 1.0f + splus(val);
        if (l < 16) s_hd[192 + l] = rr;
      }
    }
    __syncthreads();

    {
      int n = tid >> 1, half = tid & 1;
      const float* mrow = s_mem + n * MPAD + half * 32;
      const float* kp = s_hd + half * 32;
      float dot = 0.f, sq = 0.f;
      #pragma unroll
      for (int i = 0; i < 32; ++i) {
        float mv = mrow[i];
        dot = fmaf(mv, kp[i], dot);
        sq  = fmaf(mv, mv, sq);
      }
      dot += __shfl_xor(dot, 1);
      sq  += __shfl_xor(sq, 1);
      if (half == 0) s_sim[n] = dot / fmaxf(sqrtf(sq), 1e-12f);
    }
    __syncthreads();

    if (tid < 64) {
      int l = tid;
      float beta = s_hd[195], gate = s_hd[196], gamma = s_hd[197];
      float sh0 = s_hd[192], sh1 = s_hd[193], sh2 = s_hd[194];
      float v0 = beta * s_sim[l], v1 = beta * s_sim[64 + l];
      float v2 = beta * s_sim[128 + l], v3 = beta * s_sim[192 + l];
      float mx = fmaxf(fmaxf(v0, v1), fmaxf(v2, v3));
      for (int off = 32; off; off >>= 1) mx = fmaxf(mx, __shfl_xor(mx, off));
      float e0 = __expf(v0 - mx), e1 = __expf(v1 - mx);
      float e2 = __expf(v2 - mx), e3 = __expf(v3 - mx);
      float s = e0 + e1 + e2 + e3;
      for (int off = 32; off; off >>= 1) s += __shfl_xor(s, off);
      float inv = 1.0f / s, omg = 1.0f - gate;
      float wg[4];
      wg[0] = gate * e0 * inv + omg * s_rw[l];
      wg[1] = gate * e1 * inv + omg * s_rw[64 + l];
      wg[2] = gate * e2 * inv + omg * s_rw[128 + l];
      wg[3] = gate * e3 * inv + omg * s_rw[192 + l];
      float p[4]; float ps = 0.f;
      #pragma unroll
      for (int j = 0; j < 4; ++j) {
        float cu = (l == 0) ? wg[(j + 1) & 3] : wg[j];
        float up = __shfl(cu, (l + 1) & 63);
        float cd = (l == 63) ? wg[(j + 3) & 3] : wg[j];
        float dn = __shfl(cd, (l + 63) & 63);
        float wn = fmaf(sh0, up, fmaf(sh1, wg[j], sh2 * dn));
        p[j] = exp2f(gamma * __log2f(wn));
        ps += p[j];
      }
      for (int off = 32; off; off >>= 1) ps += __shfl_xor(ps, off);
      float invp = 1.0f / ps;
      #pragma unroll
      for (int j = 0; j < 4; ++j) {
        float wv = p[j] * invp;
        s_w[l + 64 * j] = wv;
        s_rw[l + 64 * j] = wv;
      }
    }
    __syncthreads();

    {
      int m = tid & 63, q = tid >> 6;
      float acc = 0.f;
      int n0 = q * 32;
      #pragma unroll
      for (int i = 0; i < 32; ++i) {
        int n = n0 + i;
        acc = fmaf(s_w[n], s_mem[n * MPAD + m], acc);
      }
      s_part[q * 64 + m] = acc;
    }
    __syncthreads();

    if (tid < NM) {
      float acc = 0.f;
      #pragma unroll
      for (int q = 0; q < 8; ++q) acc += s_part[q * 64 + tid];
      s_rv[tid] = acc;
    }
    for (int i = tid; i < NN * NM; i += 512) {
      int n = i >> 6, m = i & 63;
      float wv = s_w[n];
      float cur = s_mem[n * MPAD + m];
      s_mem[n * MPAD + m] = cur * (1.f - wv * s_hd[64 + m]) + wv * s_hd[128 + m];
    }
    __syncthreads();

    // fused logits: 4 cols x 4 k-chunks of 80
    {
      int ogo = tid & 127, qo = tid >> 7;
      const uint2* pw = OUT4 + (qo * 80) * 128 + ogo;
      float4 acc = {0.f, 0.f, 0.f, 0.f};
      #pragma unroll 8
      for (int kk = 0; kk < 80; ++kk) {
        int k = qo * 80 + kk;
        float a = (k < NC) ? s_h[k] : s_rv[k - NC];
        uint2 wv = pw[kk * 128];
        FMA4(wv, a);
      }
      s_part4[qo * 128 + ogo] = acc;
    }
    __syncthreads();
    {
      float rr2 = out_b[tid];
      #pragma unroll
      for (int q = 0; q < 4; ++q) rr2 += s_part[q * NV + tid];
      out[((size_t)(b * NS + t)) * NV + tid] = rr2;
    }
    __syncthreads();
  }
}

// ---------------- Logits GEMM: 8192 x 512, K=320, fp16 weights ----------------
__launch_bounds__(512)
__global__ void ntm_logits(const float* __restrict__ ws, const float* __restrict__ out_b,
                           float* __restrict__ out)
{
  const uint2* OUT4 = ((const uint2*)ws) + U2_OUT;
  const float* hrv = ws + F_HRV;
  __shared__ float s_z[16 * 321];
  const int tid = threadIdx.x;
  const int r0 = blockIdx.x * 16;
  {
    int r = tid >> 5, i0 = tid & 31;
    const float* src = hrv + (size_t)(r0 + r) * KZ;
    for (int i = i0; i < KZ; i += 32) s_z[r * 321 + i] = src[i];
  }
  __syncthreads();
  const int og = tid & 127, rq = tid >> 7;
  const int rb = rq * 4;
  const uint2* pw = OUT4 + og;
  float4 a0 = {0,0,0,0}, a1 = a0, a2 = a0, a3 = a0;
  #pragma unroll 4
  for (int k = 0; k < KZ; ++k) {
    uint2 w = pw[k * 128];
    float w0 = hlo(w.x), w1 = hhi(w.x), w2 = hlo(w.y), w3 = hhi(w.y);
    float z0 = s_z[(rb + 0) * 321 + k], z1 = s_z[(rb + 1) * 321 + k];
    float z2 = s_z[(rb + 2) * 321 + k], z3 = s_z[(rb + 3) * 321 + k];
    a0.x = fmaf(w0, z0, a0.x); a0.y = fmaf(w1, z0, a0.y); a0.z = fmaf(w2, z0, a0.z); a0.w = fmaf(w3, z0, a0.w);
    a1.x = fmaf(w0, z1, a1.x); a1.y = fmaf(w1, z1, a1.y); a1.z = fmaf(w2, z1, a1.z); a1.w = fmaf(w3, z1, a1.w);
    a2.x = fmaf(w0, z2, a2.x); a2.y = fmaf(w1, z2, a2.y); a2.z = fmaf(w2, z2, a2.z); a2.w = fmaf(w3, z2, a2.w);
    a3.x = fmaf(w0, z3, a3.x); a3.y = fmaf(w1, z3, a3.y); a3.z = fmaf(w2, z3, a3.z); a3.w = fmaf(w3, z3, a3.w);
  }
  float4 ob = *(const float4*)(out_b + og * 4);
  a0.x += ob.x; a0.y += ob.y; a0.z += ob.z; a0.w += ob.w;
  a1.x += ob.x; a1.y += ob.y; a1.z += ob.z; a1.w += ob.w;
  a2.x += ob.x; a2.y += ob.y; a2.z += ob.z; a2.w += ob.w;
  a3.x += ob.x; a3.y += ob.y; a3.z += ob.z; a3.w += ob.w;
  float4* po = (float4*)(out + (size_t)(r0 + rb) * NV + og * 4);
  po[0 * (NV / 4)] = a0;
  po[1 * (NV / 4)] = a1;
  po[2 * (NV / 4)] = a2;
  po[3 * (NV / 4)] = a3;
}

extern "C" void kernel_launch(void* const* d_in, const int* in_sizes, int n_in,
                              void* d_out, int out_size, void* d_ws, size_t ws_size,
                              hipStream_t stream) {
  (void)in_sizes; (void)n_in; (void)out_size;
  const int*   x       = (const int*)  d_in[0];
  const float* emb     = (const float*)d_in[1];
  const float* W_ih    = (const float*)d_in[2];
  const float* W_hh    = (const float*)d_in[3];
  const float* b_ih    = (const float*)d_in[4];
  const float* b_hh    = (const float*)d_in[5];
  const float* key_W   = (const float*)d_in[6];
  const float* key_b   = (const float*)d_in[7];
  const float* beta_W  = (const float*)d_in[8];
  const float* beta_b  = (const float*)d_in[9];
  const float* gate_W  = (const float*)d_in[10];
  const float* gate_b  = (const float*)d_in[11];
  const float* shift_W = (const float*)d_in[12];
  const float* shift_b = (const float*)d_in[13];
  const float* gamma_W = (const float*)d_in[14];
  const float* gamma_b = (const float*)d_in[15];
  const float* erase_W = (const float*)d_in[16];
  const float* erase_b = (const float*)d_in[17];
  const float* add_W   = (const float*)d_in[18];
  const float* add_b   = (const float*)d_in[19];
  const float* out_W   = (const float*)d_in[20];
  const float* out_b   = (const float*)d_in[21];
  const float* mem_init= (const float*)d_in[22];
  float* ws  = (float*)d_ws;
  float* out = (float*)d_out;

  // exchange region in the tail of out (scratch until ntm_logits overwrites all of out)
  float* xtail = out + ((size_t)OUT_FLOATS - XCHG_FLOATS);
  unsigned* xaux = (unsigned*)xtail;   // xh[2][64][256] | stp[256] | pres[64] | conf[64]
  unsigned* zaux = xaux + 32768;       // the 384 control words prep must zero

  int prep_blocks = (PREP_ITEMS + 255) / 256;
  ntm_prep<<<prep_blocks, 256, 0, stream>>>(W_ih, W_hh, b_ih, b_hh, key_W, key_b,
      beta_W, beta_b, gate_W, gate_b, shift_W, shift_b, gamma_W, gamma_b,
      erase_W, erase_b, add_W, add_b, out_W, ws, zaux);

  bool split = (ws_size >= (size_t)WS_SPLIT_BYTES);
  if (split) {
    ntm_main4<<<NB * 4, 1024, 0, stream>>>(x, emb, mem_init, ws, xaux);
    ntm_logits<<<(NB * NS) / 16, 512, 0, stream>>>(ws, out_b, out);
  } else {
    hipFuncSetAttribute((const void*)ntm_mono, hipFuncAttributeMaxDynamicSharedMemorySize,
                        SMEM_BYTES);
    ntm_mono<<<NB, 512, SMEM_BYTES, stream>>>(x, emb, out_b, mem_init, ws, out);
  }
}

// Round 9
// 1973.016 us; speedup vs baseline: 1.2996x; 1.2996x over previous
//
#include <hip/hip_runtime.h>
#include <hip/hip_fp16.h>
#include <math.h>

// Problem constants
#define NB 64
#define NS 128
#define ND 128
#define NV 512
#define NC 256
#define NN 256
#define NM 64
#define NG 1024
#define KIH 192
#define K2  448      // unified GEMV depth: [emb(128) | rv(64) | h(256)]
#define KZ  320
#define HST 208
#define MPAD 65
#define KPW 56       // k-slice per wave, mono (8 waves * 56 = 448)
#define KPW4 28      // k-slice per wave, main4 (16 waves * 28 = 448)
#define G_PER_R 28672 // 448*64 uint2 per quarter

// ws layout: fp16 weights packed as uint2 (4 halves each), then fp32 biases, then hrv
#define U2_GEND 114688      // gate weights: [4 quarters][448 k][64 ch] uint2
#define U2_OUT  128000      // head weights: [256 k][52 cq] -> 13312 uint2
#define U2_END  168960      // out weights:  [320 k][128 cq] -> 40960 uint2
#define F_BSUM 337920       // 1024 floats (= U2_END*2)
#define F_HB   338944       // 208 floats (pad to 256)
#define F_HRV  339200       // 8192*320 floats
#define WS_SPLIT_BYTES 11842560u
#define PREP_ZERO 384       // stp(256) + presence(64) + confirm(64)
#define PREP_ITEMS (U2_END + NG + HST + PREP_ZERO)

// exchange region: tail of out buffer (out = 64*128*512 floats = 16.7MB; in split
// mode the tail is scratch until ntm_logits overwrites ALL of out at the end)
#define OUT_FLOATS (NB * NS * NV)
#define XCHG_FLOATS 33280   // xh 2*64*256 + stp 256 + pres 64 + conf 64 + pad

// LDS layout (floats)
#define L_MEM 0              // 256*65
#define L_H   16640          // 256
#define L_C   16896          // 256
#define L_RW  17152          // 256
#define L_W   17408          // 256
#define L_RV  17664          // 64 (mono only)
#define L_CI  17728          // 448
#define L_HD  18176          // 208
#define L_SIM 18384          // 256
#define L_TOK 18640          // 128 (ints)
#define L_PART 18768         // 4096 (16B aligned: 18768*4 % 16 == 0)
#define L_BS  22864          // 1024 (bias sums, LDS-cached)
#define L_HB2 23888          // 208  (head biases, LDS-cached)
#define SMEM_FLOATS 24096
#define SMEM_BYTES (SMEM_FLOATS * 4)   // 96384 B -> 1 block/CU (2x exceeds 160KB)

__device__ __forceinline__ float sigf(float x) { return 1.0f / (1.0f + __expf(-x)); }
__device__ __forceinline__ float splus(float x) { return (x > 20.f) ? x : log1pf(__expf(x)); }
__device__ __forceinline__ float tanhf_fast(float x) {
  if (fabsf(x) > 15.f) return copysignf(1.f, x);
  float e = __expf(2.f * x);
  return (e - 1.f) / (e + 1.f);
}

__device__ __forceinline__ float hlo(unsigned u) {
  unsigned short s = (unsigned short)(u & 0xffffu);
  _Float16 h;
  __builtin_memcpy(&h, &s, 2);
  return (float)h;
}
__device__ __forceinline__ float hhi(unsigned u) {
  unsigned short s = (unsigned short)(u >> 16);
  _Float16 h;
  __builtin_memcpy(&h, &s, 2);
  return (float)h;
}
__device__ __forceinline__ unsigned short f2h(float f) {  // RNE
  _Float16 h = (_Float16)f;
  unsigned short s;
  __builtin_memcpy(&s, &h, 2);
  return s;
}

#define FMA4(G, A) \
  acc.x = fmaf(hlo((G).x), (A), acc.x); acc.y = fmaf(hhi((G).x), (A), acc.y); \
  acc.z = fmaf(hlo((G).y), (A), acc.z); acc.w = fmaf(hhi((G).y), (A), acc.w);

__device__ float head_w(int c, int k, const float* kW, const float* eW, const float* aW,
                        const float* sW, const float* bW, const float* gW, const float* gaW) {
  if (c < 64)  return kW[c * NC + k];
  if (c < 128) return eW[(c - 64) * NC + k];
  if (c < 192) return aW[(c - 128) * NC + k];
  if (c < 195) return sW[(c - 192) * NC + k];
  if (c == 195) return bW[k];
  if (c == 196) return gW[k];
  if (c == 197) return gaW[k];
  return 0.0f;
}

// ---------------- Preprocess: repack weights (channel-quad gate layout) ----------------
__global__ void ntm_prep(const float* __restrict__ W_ih, const float* __restrict__ W_hh,
                         const float* __restrict__ b_ih, const float* __restrict__ b_hh,
                         const float* __restrict__ key_W, const float* __restrict__ key_b,
                         const float* __restrict__ beta_W, const float* __restrict__ beta_b,
                         const float* __restrict__ gate_W, const float* __restrict__ gate_b,
                         const float* __restrict__ shift_W, const float* __restrict__ shift_b,
                         const float* __restrict__ gamma_W, const float* __restrict__ gamma_b,
                         const float* __restrict__ erase_W, const float* __restrict__ erase_b,
                         const float* __restrict__ add_W, const float* __restrict__ add_b,
                         const float* __restrict__ out_W, float* __restrict__ ws,
                         unsigned* __restrict__ zaux)
{
  uint2* w4 = (uint2*)ws;
  for (int idx = blockIdx.x * blockDim.x + threadIdx.x; idx < PREP_ITEMS;
       idx += gridDim.x * blockDim.x) {
    if (idx < U2_GEND) {
      int r = idx / G_PER_R;
      int i = idx - r * G_PER_R;
      int k = i >> 6, cp = i & 63;
      int c = (r << 6) | cp;
      float v[4];
      #pragma unroll
      for (int j = 0; j < 4; ++j) {
        int row = j * NC + c;
        v[j] = (k < KIH) ? W_ih[row * KIH + k] : W_hh[row * NC + (k - KIH)];
      }
      uint2 p;
      p.x = (unsigned)f2h(v[0]) | ((unsigned)f2h(v[1]) << 16);
      p.y = (unsigned)f2h(v[2]) | ((unsigned)f2h(v[3]) << 16);
      w4[idx] = p;
    } else if (idx < U2_OUT) {
      int i = idx - U2_GEND, k = i / 52, cq = i % 52;
      float v[4];
      #pragma unroll
      for (int j = 0; j < 4; ++j)
        v[j] = head_w(cq * 4 + j, k, key_W, erase_W, add_W, shift_W, beta_W, gate_W, gamma_W);
      uint2 p;
      p.x = (unsigned)f2h(v[0]) | ((unsigned)f2h(v[1]) << 16);
      p.y = (unsigned)f2h(v[2]) | ((unsigned)f2h(v[3]) << 16);
      w4[idx] = p;
    } else if (idx < U2_END) {
      int i = idx - U2_OUT, k = i >> 7, og = i & 127;
      float v[4];
      #pragma unroll
      for (int j = 0; j < 4; ++j) v[j] = out_W[(og * 4 + j) * KZ + k];
      uint2 p;
      p.x = (unsigned)f2h(v[0]) | ((unsigned)f2h(v[1]) << 16);
      p.y = (unsigned)f2h(v[2]) | ((unsigned)f2h(v[3]) << 16);
      w4[idx] = p;
    } else if (idx < U2_END + NG) {
      int o = idx - U2_END;
      ws[F_BSUM + o] = b_ih[o] + b_hh[o];
    } else if (idx < U2_END + NG + HST) {
      int c = idx - U2_END - NG;
      float v;
      if (c < 64)       v = key_b[c];
      else if (c < 128) v = erase_b[c - 64];
      else if (c < 192) v = add_b[c - 128];
      else if (c < 195) v = shift_b[c - 192];
      else if (c == 195) v = beta_b[0];
      else if (c == 196) v = gate_b[0];
      else               v = gamma_b[0];
      ws[F_HB + c] = v;
    } else {
      zaux[idx - (U2_END + NG + HST)] = 0u;
    }
  }
}

// ---------------- Split main: 4 blocks per batch, L2-streamed quarter weights ----------------
// Round-7 structure (proven 2373us) + ONE change: phases 8/9 merged into a single
// s_mem pass (read once: rv partial accumulate + memory update), rv combine
// deferred into next step's ci-fill / hrv-store (s_part is read-only there and
// only overwritten by gate partials AFTER the S1 barrier). 8 barriers/step.
__global__ void __launch_bounds__(1024)
ntm_main4(const int* __restrict__ x, const float* __restrict__ emb,
          const float* __restrict__ mem_init,
          const float* __restrict__ ws, unsigned* __restrict__ xaux)
{
  const int bid = blockIdx.x;
  const int b = bid & 63;
  const int r = bid >> 6;          // channel quarter
  const int tid = threadIdx.x;
  const int w = tid >> 6, lane = tid & 63;
  unsigned* xh   = xaux;           // [2][NB][NC]
  unsigned* stp  = xaux + 32768;   // per-sibling step tags [NB][4]
  unsigned* pres = xaux + 33024;   // presence bitmask [NB]
  unsigned* conf = xaux + 33088;   // confirm bitmask [NB]
  const uint2* G4   = (const uint2*)ws;
  const uint2* HWT4 = G4 + U2_GEND;
  const float* bsum = ws + F_BSUM;
  const float* hb   = ws + F_HB;
  float* hrv = (float*)(ws + F_HRV);

  __shared__ float sm[SMEM_FLOATS];
  float* s_mem = sm + L_MEM;
  float* s_h   = sm + L_H;
  float* s_c   = sm + L_C;
  float* s_rw  = sm + L_RW;
  float* s_w   = sm + L_W;
  float* s_ci  = sm + L_CI;
  float* s_hd  = sm + L_HD;
  float* s_sim = sm + L_SIM;
  int*   s_tok = (int*)(sm + L_TOK);
  float* s_part = sm + L_PART;
  float4* s_part4 = (float4*)s_part;
  float* s_bs  = sm + L_BS;
  float* s_hb  = sm + L_HB2;

  for (int i = tid; i < NN * NM; i += 1024) {
    int n = i >> 6, m = i & 63;
    s_mem[n * MPAD + m] = mem_init[(size_t)b * (NN * NM) + i];
  }
  if (tid < NS) s_tok[tid] = x[b * NS + tid];
  if (tid < NC) { s_h[tid] = 0.f; s_c[tid] = 0.f; }
  if (tid < NN) s_rw[tid] = 0.f;
  s_part[tid] = 0.f;                 // rv partials = 0 at t=0
  if (tid < NG) s_bs[tid] = bsum[tid];
  if (tid < HST) s_hb[tid] = hb[tid];
  __syncthreads();

  // ---- co-residency handshake (bounded; cannot deadlock) ----
  if (tid == 0) {
    __hip_atomic_fetch_or(pres + b, 1u << r, __ATOMIC_RELEASE, __HIP_MEMORY_SCOPE_AGENT);
    int ok = 0;
    for (int i = 0; i < 40000; ++i) {
      if (__hip_atomic_load(pres + b, __ATOMIC_ACQUIRE, __HIP_MEMORY_SCOPE_AGENT) == 15u) {
        ok = 1; break;
      }
      __builtin_amdgcn_s_sleep(2);
    }
    int ok2 = 0;
    if (ok) {
      __hip_atomic_fetch_or(conf + b, 1u << r, __ATOMIC_RELEASE, __HIP_MEMORY_SCOPE_AGENT);
      for (int i = 0; i < 80000; ++i) {
        if (__hip_atomic_load(conf + b, __ATOMIC_ACQUIRE, __HIP_MEMORY_SCOPE_AGENT) == 15u) {
          ok2 = 1; break;
        }
        __builtin_amdgcn_s_sleep(2);
      }
    }
    ((int*)sm)[L_SIM] = ok2;
  }
  __syncthreads();
  const bool coop = (((int*)sm)[L_SIM] != 0);
  __syncthreads();
  if (!coop && r != 0) return;   // fallback: only r==0 continues, self-contained

  const int rq_lo = coop ? r : 0;      // quarters this block computes
  const int rq_hi = coop ? r + 1 : 4;

  for (int t = 0; t < NS; ++t) {
    // ---- phase A: ci = [emb, rv(sum of partials), h_prev]; hrv store for t-1 ----
    if (tid < K2) {
      int tok = s_tok[t];
      float v;
      if (tid < ND) v = emb[tok * ND + tid];
      else if (tid < KIH) {
        int m = tid - ND;
        float a = 0.f;
        #pragma unroll
        for (int q = 0; q < 16; ++q) a += s_part[q * 64 + m];
        v = a;
      } else v = s_h[tid - KIH];
      s_ci[tid] = v;
    }
    if (t > 0) {
      if (coop) {
        if (tid >= 448 && tid < 528) {    // 80 floats per sibling (wave 7)
          int i = tid - 448;
          float* dst = hrv + (size_t)(b * NS + (t - 1)) * KZ;
          if (i < 64) dst[r * 64 + i] = s_h[r * 64 + i];
          else {
            int m = r * 16 + (i - 64);
            float a = 0.f;
            #pragma unroll
            for (int q = 0; q < 16; ++q) a += s_part[q * 64 + m];
            dst[256 + m] = a;
          }
        }
      } else if (tid >= 448 && tid < 768) {
        int i = tid - 448;
        float v;
        if (i < NC) v = s_h[i];
        else {
          int m = i - NC;
          float a = 0.f;
          #pragma unroll
          for (int q = 0; q < 16; ++q) a += s_part[q * 64 + m];
          v = a;
        }
        hrv[(size_t)(b * NS + (t - 1)) * KZ + i] = v;
      }
    }
    __syncthreads();  // S1

    // ---- phase 2/3: gate GEMV (L2-streamed) + LSTM cell, per owned quarter ----
    for (int rr = rq_lo; rr < rq_hi; ++rr) {
      {
        float4 acc = {0.f, 0.f, 0.f, 0.f};
        const uint2* gp = G4 + rr * G_PER_R + (w * KPW4) * 64 + lane;
        const float* cip = s_ci + w * KPW4;
        #pragma unroll
        for (int kk = 0; kk < KPW4; kk += 4) {
          uint2 g0 = gp[(kk + 0) * 64];
          uint2 g1 = gp[(kk + 1) * 64];
          uint2 g2 = gp[(kk + 2) * 64];
          uint2 g3 = gp[(kk + 3) * 64];
          float4 a4 = *(const float4*)(cip + kk);
          FMA4(g0, a4.x);
          FMA4(g1, a4.y);
          FMA4(g2, a4.z);
          FMA4(g3, a4.w);
        }
        s_part4[w * 64 + lane] = acc;
      }
      __syncthreads();  // S2
      if (tid < 64) {
        int c = (rr << 6) | tid;
        float gi = s_bs[c], gf = s_bs[NC + c], gg = s_bs[2 * NC + c], go = s_bs[3 * NC + c];
        #pragma unroll
        for (int q = 0; q < 16; ++q) {
          float4 p = s_part4[q * 64 + tid];
          gi += p.x; gf += p.y; gg += p.z; go += p.w;
        }
        if (coop) {
          float cn = sigf(gf) * s_c[tid] + sigf(gi) * tanhf_fast(gg);
          s_c[tid] = cn;
          float hn = sigf(go) * tanhf_fast(cn);
          s_h[c] = hn;   // own chunk: straight to LDS
          __hip_atomic_store(xh + (t & 1) * (NB * NC) + b * NC + c, __float_as_uint(hn),
                             __ATOMIC_RELAXED, __HIP_MEMORY_SCOPE_AGENT);
        } else {
          float cn = sigf(gf) * s_c[c] + sigf(gi) * tanhf_fast(gg);
          s_c[c] = cn;
          s_h[c] = sigf(go) * tanhf_fast(cn);
        }
      }
      if (!coop) __syncthreads();
    }

    if (coop) {
      // ---- exchange: release tag, relaxed per-sibling polls, relaxed gather ----
      if (tid == 0) {
        __hip_atomic_store(stp + b * 4 + r, (unsigned)(t + 1),
                           __ATOMIC_RELEASE, __HIP_MEMORY_SCOPE_AGENT);
      } else if (w >= 1 && w <= 3) {
        int sib = (r + w) & 3;
        const unsigned tgt = (unsigned)(t + 1);
        while (__hip_atomic_load(stp + b * 4 + sib, __ATOMIC_RELAXED,
                                 __HIP_MEMORY_SCOPE_AGENT) < tgt) {}
        unsigned hv = __hip_atomic_load(xh + (t & 1) * (NB * NC) + b * NC + (sib << 6) + lane,
                                        __ATOMIC_RELAXED, __HIP_MEMORY_SCOPE_AGENT);
        s_h[(sib << 6) + lane] = __uint_as_float(hv);
      }
      __syncthreads();  // S3
    }

    // ---- phase 4: head-linear partials (52 col-quads x 16 k-chunks of 16) ----
    if (tid < 832) {
      int cq = tid % 52, q = tid / 52;
      float4 acc = {0.f, 0.f, 0.f, 0.f};
      const uint2* ph = HWT4 + (q * 16) * 52 + cq;
      const float* hp = s_h + q * 16;
      #pragma unroll
      for (int kk = 0; kk < 16; ++kk) {
        uint2 wv = ph[kk * 52];
        float a = hp[kk];
        FMA4(wv, a);
      }
      s_part4[q * 52 + cq] = acc;
    }
    __syncthreads();  // S4

    // ---- phase 5: combine + activations (wave-aligned) ----
    if (tid < 256) {
      float val = 0.f;
      if (tid < HST) {
        val = s_hb[tid];
        #pragma unroll
        for (int q = 0; q < 16; ++q) val += s_part[q * HST + tid];
      }
      int wv = tid >> 6;
      if (wv == 0) {            // key l2-normalize
        float ss = val * val;
        for (int off = 32; off; off >>= 1) ss += __shfl_xor(ss, off);
        s_hd[tid] = val / fmaxf(sqrtf(ss), 1e-12f);
      } else if (wv == 1) {     // erase: sigmoid
        s_hd[tid] = sigf(val);
      } else if (wv == 2) {     // add: tanh
        s_hd[tid] = tanhf_fast(val);
      } else {                  // wave 3: shift softmax + scalars
        int l = tid & 63;
        float a0 = __shfl(val, 0), a1 = __shfl(val, 1), a2 = __shfl(val, 2);
        float mx = fmaxf(a0, fmaxf(a1, a2));
        float e0 = __expf(a0 - mx), e1 = __expf(a1 - mx), e2 = __expf(a2 - mx);
        float ss = e0 + e1 + e2;
        float rr = 0.f;
        if (l == 0) rr = e0 / ss;
        else if (l == 1) rr = e1 / ss;
        else if (l == 2) rr = e2 / ss;
        else if (l == 3) rr = splus(val);          // beta  (col 195)
        else if (l == 4) rr = sigf(val);           // gate  (col 196)
        else if (l == 5) rr = 1.0f + splus(val);   // gamma (col 197)
        if (l < 16) s_hd[192 + l] = rr;
      }
    }
    __syncthreads();  // S5

    // ---- phase 6: cosine sim (4 lanes per memory row) ----
    {
      int n = tid >> 2, qq = tid & 3;
      const float* mrow = s_mem + n * MPAD + qq * 16;
      const float* kp = s_hd + qq * 16;
      float dot = 0.f, sq = 0.f;
      #pragma unroll
      for (int i = 0; i < 16; ++i) {
        float mv = mrow[i];
        dot = fmaf(mv, kp[i], dot);
        sq  = fmaf(mv, mv, sq);
      }
      dot += __shfl_xor(dot, 1); dot += __shfl_xor(dot, 2);
      sq  += __shfl_xor(sq, 1);  sq  += __shfl_xor(sq, 2);
      if (qq == 0) s_sim[n] = dot / fmaxf(sqrtf(sq), 1e-12f);
    }
    __syncthreads();  // S6

    // ---- phase 7: addressing chain in one wave (4 slots/lane) ----
    if (tid < 64) {
      int l = tid;
      float beta = s_hd[195], gate = s_hd[196], gamma = s_hd[197];
      float sh0 = s_hd[192], sh1 = s_hd[193], sh2 = s_hd[194];
      float v0 = beta * s_sim[l], v1 = beta * s_sim[64 + l];
      float v2 = beta * s_sim[128 + l], v3 = beta * s_sim[192 + l];
      float mx = fmaxf(fmaxf(v0, v1), fmaxf(v2, v3));
      for (int off = 32; off; off >>= 1) mx = fmaxf(mx, __shfl_xor(mx, off));
      float e0 = __expf(v0 - mx), e1 = __expf(v1 - mx);
      float e2 = __expf(v2 - mx), e3 = __expf(v3 - mx);
      float s = e0 + e1 + e2 + e3;
      for (int off = 32; off; off >>= 1) s += __shfl_xor(s, off);
      float inv = 1.0f / s, omg = 1.0f - gate;
      float wg[4];
      wg[0] = gate * e0 * inv + omg * s_rw[l];
      wg[1] = gate * e1 * inv + omg * s_rw[64 + l];
      wg[2] = gate * e2 * inv + omg * s_rw[128 + l];
      wg[3] = gate * e3 * inv + omg * s_rw[192 + l];
      float p[4]; float ps = 0.f;
      #pragma unroll
      for (int j = 0; j < 4; ++j) {
        float cu = (l == 0) ? wg[(j + 1) & 3] : wg[j];
        float up = __shfl(cu, (l + 1) & 63);
        float cd = (l == 63) ? wg[(j + 3) & 3] : wg[j];
        float dn = __shfl(cd, (l + 63) & 63);
        float wn = fmaf(sh0, up, fmaf(sh1, wg[j], sh2 * dn));
        p[j] = exp2f(gamma * __log2f(wn));   // w^gamma, w>=0 (log2(0)=-inf -> 0)
        ps += p[j];
      }
      for (int off = 32; off; off >>= 1) ps += __shfl_xor(ps, off);
      float invp = 1.0f / ps;
      #pragma unroll
      for (int j = 0; j < 4; ++j) {
        float wv = p[j] * invp;
        s_w[l + 64 * j] = wv;
        s_rw[l + 64 * j] = wv;
      }
    }
    __syncthreads();  // S7

    // ---- phase 8: rv partials + memory update in ONE s_mem pass ----
    {
      int m = tid & 63, q = tid >> 6;
      float er = s_hd[64 + m], ad = s_hd[128 + m];
      float acc = 0.f;
      int n0 = q * 16;
      #pragma unroll
      for (int i = 0; i < 16; ++i) {
        int n = n0 + i;
        float wv = s_w[n];
        float v = s_mem[n * MPAD + m];
        acc = fmaf(wv, v, acc);
        s_mem[n * MPAD + m] = v * (1.f - wv * er) + wv * ad;
      }
      s_part[q * 64 + m] = acc;   // combined into ci / hrv next step
    }
    __syncthreads();  // S8
  }

  // final hrv store (rv summed from partials of t = NS-1)
  if (coop) {
    if (tid >= 448 && tid < 528) {
      int i = tid - 448;
      float* dst = hrv + (size_t)(b * NS + NS - 1) * KZ;
      if (i < 64) dst[r * 64 + i] = s_h[r * 64 + i];
      else {
        int m = r * 16 + (i - 64);
        float a = 0.f;
        #pragma unroll
        for (int q = 0; q < 16; ++q) a += s_part[q * 64 + m];
        dst[256 + m] = a;
      }
    }
  } else if (tid >= 448 && tid < 768) {
    int i = tid - 448;
    float v;
    if (i < NC) v = s_h[i];
    else {
      int m = i - NC;
      float a = 0.f;
      #pragma unroll
      for (int q = 0; q < 16; ++q) a += s_part[q * 64 + m];
      v = a;
    }
    hrv[(size_t)(b * NS + NS - 1) * KZ + i] = v;
  }
}

// ---------------- Mono fallback (small ws): one block per batch, streamed weights ----------------
__launch_bounds__(512, 1)
__global__ void ntm_mono(const int* __restrict__ x, const float* __restrict__ emb,
                         const float* __restrict__ out_b, const float* __restrict__ mem_init,
                         const float* __restrict__ ws, float* __restrict__ out)
{
  const int b = blockIdx.x;
  const int tid = threadIdx.x;
  const int w = tid >> 6, lane = tid & 63;
  const uint2* G4   = (const uint2*)ws;
  const uint2* HWT4 = G4 + U2_GEND;
  const uint2* OUT4 = G4 + U2_OUT;
  const float* bsum = ws + F_BSUM;
  const float* hb   = ws + F_HB;

  extern __shared__ float sm[];
  float* s_mem = sm + L_MEM;
  float* s_h   = sm + L_H;
  float* s_c   = sm + L_C;
  float* s_rw  = sm + L_RW;
  float* s_w   = sm + L_W;
  float* s_rv  = sm + L_RV;
  float* s_ci  = sm + L_CI;
  float* s_hd  = sm + L_HD;
  float* s_sim = sm + L_SIM;
  int*   s_tok = (int*)(sm + L_TOK);
  float* s_part = sm + L_PART;
  float4* s_part4 = (float4*)s_part;

  for (int i = tid; i < NN * NM; i += 512) {
    int n = i >> 6, m = i & 63;
    s_mem[n * MPAD + m] = mem_init[(size_t)b * (NN * NM) + i];
  }
  if (tid < NS) s_tok[tid] = x[b * NS + tid];
  if (tid < NC) { s_h[tid] = 0.f; s_c[tid] = 0.f; }
  if (tid < NN) s_rw[tid] = 0.f;
  if (tid < NM) s_rv[tid] = 0.f;
  __syncthreads();

  for (int t = 0; t < NS; ++t) {
    if (tid < K2) {
      int tok = s_tok[t];
      s_ci[tid] = (tid < ND) ? emb[tok * ND + tid]
                : (tid < KIH) ? s_rv[tid - ND] : s_h[tid - KIH];
    }
    __syncthreads();

    for (int rr = 0; rr < 4; ++rr) {
      {
        float4 acc = {0.f, 0.f, 0.f, 0.f};
        const uint2* gp = G4 + rr * G_PER_R + (w * KPW) * 64 + lane;
        const float* cip = s_ci + w * KPW;
        #pragma unroll 8
        for (int kk = 0; kk < KPW; ++kk) {
          uint2 g = gp[kk * 64];
          float a = cip[kk];
          FMA4(g, a);
        }
        s_part4[w * 64 + lane] = acc;
      }
      __syncthreads();
      if (tid < 64) {
        int c = (rr << 6) | tid;
        float gi = bsum[c], gf = bsum[NC + c], gg = bsum[2 * NC + c], go = bsum[3 * NC + c];
        #pragma unroll
        for (int q = 0; q < 8; ++q) {
          float4 p = s_part4[q * 64 + tid];
          gi += p.x; gf += p.y; gg += p.z; go += p.w;
        }
        float cn = sigf(gf) * s_c[c] + sigf(gi) * tanhf_fast(gg);
        s_c[c] = cn;
        s_h[c] = sigf(go) * tanhf_fast(cn);
      }
      __syncthreads();
    }

    if (tid < 416) {
      int cq = tid % 52, q = tid / 52;
      float4 acc = {0.f, 0.f, 0.f, 0.f};
      const uint2* ph = HWT4 + (q * 32) * 52 + cq;
      const float* hp = s_h + q * 32;
      #pragma unroll 8
      for (int kk = 0; kk < 32; ++kk) {
        uint2 wv = ph[kk * 52];
        float a = hp[kk];
        FMA4(wv, a);
      }
      s_part4[q * 52 + cq] = acc;
    }
    __syncthreads();

    if (tid < 256) {
      float val = 0.f;
      if (tid < HST) {
        val = hb[tid];
        #pragma unroll
        for (int q = 0; q < 8; ++q) val += s_part[q * HST + tid];
      }
      int wv = tid >> 6;
      if (wv == 0) {
        float ss = val * val;
        for (int off = 32; off; off >>= 1) ss += __shfl_xor(ss, off);
        s_hd[tid] = val / fmaxf(sqrtf(ss), 1e-12f);
      } else if (wv == 1) {
        s_hd[tid] = sigf(val);
      } else if (wv == 2) {
        s_hd[tid] = tanhf_fast(val);
      } else {
        int l = tid & 63;
        float a0 = __shfl(val, 0), a1 = __shfl(val, 1), a2 = __shfl(val, 2);
        float mx = fmaxf(a0, fmaxf(a1, a2));
        float e0 = __expf(a0 - mx), e1 = __expf(a1 - mx), e2 = __expf(a2 - mx);
        float ss = e0 + e1 + e2;
        float rr = 0.f;
        if (l == 0) rr = e0 / ss;
        else if (l == 1) rr = e1 / ss;
        else if (l == 2) rr = e2 / ss;
        else if (l == 3) rr = splus(val);
        else if (l == 4) rr = sigf(val);
        else if (l == 5) rr = 1.0f + splus(val);
        if (l < 16) s_hd[192 + l] = rr;
      }
    }
    __syncthreads();

    {
      int n = tid >> 1, half = tid & 1;
      const float* mrow = s_mem + n * MPAD + half * 32;
      const float* kp = s_hd + half * 32;
      float dot = 0.f, sq = 0.f;
      #pragma unroll
      for (int i = 0; i < 32; ++i) {
        float mv = mrow[i];
        dot = fmaf(mv, kp[i], dot);
        sq  = fmaf(mv, mv, sq);
      }
      dot += __shfl_xor(dot, 1);
      sq  += __shfl_xor(sq, 1);
      if (half == 0) s_sim[n] = dot / fmaxf(sqrtf(sq), 1e-12f);
    }
    __syncthreads();

    if (tid < 64) {
      int l = tid;
      float beta = s_hd[195], gate = s_hd[196], gamma = s_hd[197];
      float sh0 = s_hd[192], sh1 = s_hd[193], sh2 = s_hd[194];
      float v0 = beta * s_sim[l], v1 = beta * s_sim[64 + l];
      float v2 = beta * s_sim[128 + l], v3 = beta * s_sim[192 + l];
      float mx = fmaxf(fmaxf(v0, v1), fmaxf(v2, v3));
      for (int off = 32; off; off >>= 1) mx = fmaxf(mx, __shfl_xor(mx, off));
      float e0 = __expf(v0 - mx), e1 = __expf(v1 - mx);
      float e2 = __expf(v2 - mx), e3 = __expf(v3 - mx);
      float s = e0 + e1 + e2 + e3;
      for (int off = 32; off; off >>= 1) s += __shfl_xor(s, off);
      float inv = 1.0f / s, omg = 1.0f - gate;
      float wg[4];
      wg[0] = gate * e0 * inv + omg * s_rw[l];
      wg[1] = gate * e1 * inv + omg * s_rw[64 + l];
      wg[2] = gate * e2 * inv + omg * s_rw[128 + l];
      wg[3] = gate * e3 * inv + omg * s_rw[192 + l];
      float p[4]; float ps = 0.f;
      #pragma unroll
      for (int j = 0; j < 4; ++j) {
        float cu = (l == 0) ? wg[(j + 1) & 3] : wg[j];
        float up = __shfl(cu, (l + 1) & 63);
        float cd = (l == 63) ? wg[(j + 3) & 3] : wg[j];
        float dn = __shfl(cd, (l + 63) & 63);
        float wn = fmaf(sh0, up, fmaf(sh1, wg[j], sh2 * dn));
        p[j] = exp2f(gamma * __log2f(wn));
        ps += p[j];
      }
      for (int off = 32; off; off >>= 1) ps += __shfl_xor(ps, off);
      float invp = 1.0f / ps;
      #pragma unroll
      for (int j = 0; j < 4; ++j) {
        float wv = p[j] * invp;
        s_w[l + 64 * j] = wv;
        s_rw[l + 64 * j] = wv;
      }
    }
    __syncthreads();

    {
      int m = tid & 63, q = tid >> 6;
      float acc = 0.f;
      int n0 = q * 32;
      #pragma unroll
      for (int i = 0; i < 32; ++i) {
        int n = n0 + i;
        acc = fmaf(s_w[n], s_mem[n * MPAD + m], acc);
      }
      s_part[q * 64 + m] = acc;
    }
    __syncthreads();

    if (tid < NM) {
      float acc = 0.f;
      #pragma unroll
      for (int q = 0; q < 8; ++q) acc += s_part[q * 64 + tid];
      s_rv[tid] = acc;
    }
    for (int i = tid; i < NN * NM; i += 512) {
      int n = i >> 6, m = i & 63;
      float wv = s_w[n];
      float cur = s_mem[n * MPAD + m];
      s_mem[n * MPAD + m] = cur * (1.f - wv * s_hd[64 + m]) + wv * s_hd[128 + m];
    }
    __syncthreads();

    // fused logits: 4 cols x 4 k-chunks of 80
    {
      int ogo = tid & 127, qo = tid >> 7;
      const uint2* pw = OUT4 + (qo * 80) * 128 + ogo;
      float4 acc = {0.f, 0.f, 0.f, 0.f};
      #pragma unroll 8
      for (int kk = 0; kk < 80; ++kk) {
        int k = qo * 80 + kk;
        float a = (k < NC) ? s_h[k] : s_rv[k - NC];
        uint2 wv = pw[kk * 128];
        FMA4(wv, a);
      }
      s_part4[qo * 128 + ogo] = acc;
    }
    __syncthreads();
    {
      float rr2 = out_b[tid];
      #pragma unroll
      for (int q = 0; q < 4; ++q) rr2 += s_part[q * NV + tid];
      out[((size_t)(b * NS + t)) * NV + tid] = rr2;
    }
    __syncthreads();
  }
}

// ---------------- Logits GEMM: 8192 x 512, K=320, fp16 weights ----------------
__launch_bounds__(512)
__global__ void ntm_logits(const float* __restrict__ ws, const float* __restrict__ out_b,
                           float* __restrict__ out)
{
  const uint2* OUT4 = ((const uint2*)ws) + U2_OUT;
  const float* hrv = ws + F_HRV;
  __shared__ float s_z[16 * 321];
  const int tid = threadIdx.x;
  const int r0 = blockIdx.x * 16;
  {
    int r = tid >> 5, i0 = tid & 31;
    const float* src = hrv + (size_t)(r0 + r) * KZ;
    for (int i = i0; i < KZ; i += 32) s_z[r * 321 + i] = src[i];
  }
  __syncthreads();
  const int og = tid & 127, rq = tid >> 7;
  const int rb = rq * 4;
  const uint2* pw = OUT4 + og;
  float4 a0 = {0,0,0,0}, a1 = a0, a2 = a0, a3 = a0;
  #pragma unroll 4
  for (int k = 0; k < KZ; ++k) {
    uint2 w = pw[k * 128];
    float w0 = hlo(w.x), w1 = hhi(w.x), w2 = hlo(w.y), w3 = hhi(w.y);
    float z0 = s_z[(rb + 0) * 321 + k], z1 = s_z[(rb + 1) * 321 + k];
    float z2 = s_z[(rb + 2) * 321 + k], z3 = s_z[(rb + 3) * 321 + k];
    a0.x = fmaf(w0, z0, a0.x); a0.y = fmaf(w1, z0, a0.y); a0.z = fmaf(w2, z0, a0.z); a0.w = fmaf(w3, z0, a0.w);
    a1.x = fmaf(w0, z1, a1.x); a1.y = fmaf(w1, z1, a1.y); a1.z = fmaf(w2, z1, a1.z); a1.w = fmaf(w3, z1, a1.w);
    a2.x = fmaf(w0, z2, a2.x); a2.y = fmaf(w1, z2, a2.y); a2.z = fmaf(w2, z2, a2.z); a2.w = fmaf(w3, z2, a2.w);
    a3.x = fmaf(w0, z3, a3.x); a3.y = fmaf(w1, z3, a3.y); a3.z = fmaf(w2, z3, a3.z); a3.w = fmaf(w3, z3, a3.w);
  }
  float4 ob = *(const float4*)(out_b + og * 4);
  a0.x += ob.x; a0.y += ob.y; a0.z += ob.z; a0.w += ob.w;
  a1.x += ob.x; a1.y += ob.y; a1.z += ob.z; a1.w += ob.w;
  a2.x += ob.x; a2.y += ob.y; a2.z += ob.z; a2.w += ob.w;
  a3.x += ob.x; a3.y += ob.y; a3.z += ob.z; a3.w += ob.w;
  float4* po = (float4*)(out + (size_t)(r0 + rb) * NV + og * 4);
  po[0 * (NV / 4)] = a0;
  po[1 * (NV / 4)] = a1;
  po[2 * (NV / 4)] = a2;
  po[3 * (NV / 4)] = a3;
}

extern "C" void kernel_launch(void* const* d_in, const int* in_sizes, int n_in,
                              void* d_out, int out_size, void* d_ws, size_t ws_size,
                              hipStream_t stream) {
  (void)in_sizes; (void)n_in; (void)out_size;
  const int*   x       = (const int*)  d_in[0];
  const float* emb     = (const float*)d_in[1];
  const float* W_ih    = (const float*)d_in[2];
  const float* W_hh    = (const float*)d_in[3];
  const float* b_ih    = (const float*)d_in[4];
  const float* b_hh    = (const float*)d_in[5];
  const float* key_W   = (const float*)d_in[6];
  const float* key_b   = (const float*)d_in[7];
  const float* beta_W  = (const float*)d_in[8];
  const float* beta_b  = (const float*)d_in[9];
  const float* gate_W  = (const float*)d_in[10];
  const float* gate_b  = (const float*)d_in[11];
  const float* shift_W = (const float*)d_in[12];
  const float* shift_b = (const float*)d_in[13];
  const float* gamma_W = (const float*)d_in[14];
  const float* gamma_b = (const float*)d_in[15];
  const float* erase_W = (const float*)d_in[16];
  const float* erase_b = (const float*)d_in[17];
  const float* add_W   = (const float*)d_in[18];
  const float* add_b   = (const float*)d_in[19];
  const float* out_W   = (const float*)d_in[20];
  const float* out_b   = (const float*)d_in[21];
  const float* mem_init= (const float*)d_in[22];
  float* ws  = (float*)d_ws;
  float* out = (float*)d_out;

  // exchange region in the tail of out (scratch until ntm_logits overwrites all of out)
  float* xtail = out + ((size_t)OUT_FLOATS - XCHG_FLOATS);
  unsigned* xaux = (unsigned*)xtail;   // xh[2][64][256] | stp[256] | pres[64] | conf[64]
  unsigned* zaux = xaux + 32768;       // the 384 control words prep must zero

  int prep_blocks = (PREP_ITEMS + 255) / 256;
  ntm_prep<<<prep_blocks, 256, 0, stream>>>(W_ih, W_hh, b_ih, b_hh, key_W, key_b,
      beta_W, beta_b, gate_W, gate_b, shift_W, shift_b, gamma_W, gamma_b,
      erase_W, erase_b, add_W, add_b, out_W, ws, zaux);

  bool split = (ws_size >= (size_t)WS_SPLIT_BYTES);
  if (split) {
    ntm_main4<<<NB * 4, 1024, 0, stream>>>(x, emb, mem_init, ws, xaux);
    ntm_logits<<<(NB * NS) / 16, 512, 0, stream>>>(ws, out_b, out);
  } else {
    hipFuncSetAttribute((const void*)ntm_mono, hipFuncAttributeMaxDynamicSharedMemorySize,
                        SMEM_BYTES);
    ntm_mono<<<NB, 512, SMEM_BYTES, stream>>>(x, emb, out_b, mem_init, ws, out);
  }
}